// Round 1
// 1545.924 us; speedup vs baseline: 1.2202x; 1.2202x over previous
//
#include <hip/hip_runtime.h>
#include <cstdint>
#include <cstddef>

// ---------------------------------------------------------------------------
// Llama decoder layer, MI355X. B=2 S=1024 H=4096 NQ=32 NKV=8 D=128 I=11008.
// R3: all GEMMs moved to a 256-wide-N pipelined MFMA kernel (8 waves, BK=64,
// XOR-swizzled LDS staged by global_load_lds with pre-swizzled source,
// 4 phases/K-tile with counted vmcnt(4) -- never drained in steady state,
// s_setprio around MFMA clusters).  BM=256 for QKV/GU, BM=128 for WO/down.
// ---------------------------------------------------------------------------

typedef __bf16 bf16;
typedef __attribute__((ext_vector_type(8))) __bf16 bf16x8;
typedef __attribute__((ext_vector_type(4))) float f32x4;

#define GLDS16(gptr, lptr)                                                    \
  __builtin_amdgcn_global_load_lds(                                           \
      (const __attribute__((address_space(1))) void*)(gptr),                  \
      (__attribute__((address_space(3))) void*)(lptr), 16, 0, 0)

#define S_LEN 1024
#define H_DIM 4096
#define NQ_H 32
#define NKV_H 8
#define HD 128
#define I_DIM 11008

// ---------------------------------------------------------------------------
// Weight transpose + fp32->bf16, 64x64 tiles, vectorized.
// src [K][N] f32 -> dst[( (n>>7)*tile_stride + (n&127) + base )][K] bf16.
// ---------------------------------------------------------------------------
__global__ __launch_bounds__(256) void wtrans64_kernel(
    const float* __restrict__ src, bf16* __restrict__ dst, int K, int N,
    int tile_stride, int base) {
  const int tid = threadIdx.x;
  const int n0 = blockIdx.x * 64, k0 = blockIdx.y * 64;
  __shared__ float t[64][65];
  const int r = tid >> 4, c4 = (tid & 15) * 4;
#pragma unroll
  for (int j = 0; j < 4; j++) {
    const float4 v =
        *(const float4*)&src[(size_t)(k0 + r + j * 16) * N + n0 + c4];
    t[r + j * 16][c4 + 0] = v.x;
    t[r + j * 16][c4 + 1] = v.y;
    t[r + j * 16][c4 + 2] = v.z;
    t[r + j * 16][c4 + 3] = v.w;
  }
  __syncthreads();
  const int n = tid >> 2, kq = (tid & 3) * 16;
  bf16x8 o0, o1;
#pragma unroll
  for (int i = 0; i < 8; i++) {
    o0[i] = (bf16)t[kq + i][n];
    o1[i] = (bf16)t[kq + 8 + i][n];
  }
  const int ng = n0 + n;
  const size_t orow = (size_t)(ng >> 7) * tile_stride + (ng & 127) + base;
  *(bf16x8*)&dst[orow * K + k0 + kq] = o0;
  *(bf16x8*)&dst[orow * K + k0 + kq + 8] = o1;
}

// ---------------------------------------------------------------------------
// RMSNorm: x f32 [rows][4096] -> out bf16, one block per row
// ---------------------------------------------------------------------------
__global__ __launch_bounds__(256) void rmsnorm_kernel(
    const float* __restrict__ x, const float* __restrict__ w,
    bf16* __restrict__ out) {
  const int row = blockIdx.x;
  const float4* xr = (const float4*)(x + (size_t)row * H_DIM);
  float4 v[4];
  float s = 0.f;
#pragma unroll
  for (int i = 0; i < 4; i++) {
    v[i] = xr[threadIdx.x + i * 256];
    s += v[i].x * v[i].x + v[i].y * v[i].y + v[i].z * v[i].z + v[i].w * v[i].w;
  }
#pragma unroll
  for (int m = 1; m < 64; m <<= 1) s += __shfl_xor(s, m);
  __shared__ float red[4];
  if ((threadIdx.x & 63) == 0) red[threadIdx.x >> 6] = s;
  __syncthreads();
  s = red[0] + red[1] + red[2] + red[3];
  const float r = rsqrtf(s * (1.f / H_DIM) + 1e-5f);
  bf16* o = out + (size_t)row * H_DIM;
  const float4* wr = (const float4*)w;
#pragma unroll
  for (int i = 0; i < 4; i++) {
    float4 wv = wr[threadIdx.x + i * 256];
    int idx = (threadIdx.x + i * 256) * 4;
    o[idx + 0] = (bf16)(v[i].x * r * wv.x);
    o[idx + 1] = (bf16)(v[i].y * r * wv.y);
    o[idx + 2] = (bf16)(v[i].z * r * wv.z);
    o[idx + 3] = (bf16)(v[i].w * r * wv.w);
  }
}

// ---------------------------------------------------------------------------
// Pipelined GEMM TN: C[M][Ncols] = A[M][K](bf16) * Bt[Ncols][K](bf16)^T.
// BN = 256 fixed. BM template (256 or 128). BK = 64. 512 threads = 8 waves
// (2 M x 4 N), per-wave output (BM/2) x 64, MFMA 16x16x32.
//
// LDS: 2-K-tile ring, [A: BM x 64 | B: 256 x 64] bf16 per buffer.
// Rows are 128 B; logical colbyte cb stored at physical cb ^ ((row&7)<<4).
// global_load_lds writes LINEARLY (wave base + lane*16); the source global
// address carries the inverse swizzle, the ds_read applies the same XOR
// -> every 8-lane group covers all 8 16B slots of a row: conflict-free.
//
// Schedule per K-tile t (4 phases, 2 barriers each):
//   p0: read A-quad0 + B-quad0 ; stage A(t+1) half0 -> buf^1 ; mfma (0,0)
//   p1: read B-quad1           ; stage A(t+1) half1 -> buf^1 ; mfma (0,1)
//   p2: read A-quad1           ; stage B(t+2) half0 -> buf   ; mfma (1,0)
//   p3:                          stage B(t+2) half1 -> buf   ; mfma (1,1)
//       then s_waitcnt vmcnt(4)  (leaves only the two B(t+2) halves in
//       flight; everything tile t+1 needs has landed), barrier.
// WAR is safe: each staged half's previous occupant was last read >=1
// barrier before the stage issues.  vmcnt never drains to 0 until epilogue.
// MODE 0: bf16 out. MODE 2: f32 out + resid add.
// ---------------------------------------------------------------------------
template <int BM, int MODE>
__global__ __launch_bounds__(512, 2) void gemm256(
    const bf16* __restrict__ A, const bf16* __restrict__ Bt,
    void* __restrict__ Cout, const float* __restrict__ resid, int N, int K,
    int mshift) {
  constexpr int MREP = BM / 32;         // m-fragments per wave (8 / 4)
  constexpr int MQ = MREP / 2;          // fragments per m-quadrant (4 / 2)
  constexpr int LA = BM / 128;          // GLDS16 per thread per A-half (2 / 1)
  constexpr int ABYTES = BM * 128;      // A region bytes per buffer
  constexpr int BUFB = ABYTES + 32768;  // + B region (256 rows x 128 B)
  __shared__ __align__(16) char smem[2 * BUFB];

  const int tid = threadIdx.x;
  const int w = tid >> 6, lane = tid & 63;
  const int lr = lane & 15, quad = lane >> 4;
  const int wm = w & 1, wn = w >> 1;
  const int m0 = (blockIdx.x & ((1 << mshift) - 1)) * BM;
  const int n0 = (blockIdx.x >> mshift) * 256;
  const int NT = K >> 6;

  // staging source geometry: linear LDS dest o = j*8192 + w*1024 + lane*16
  // -> row r = j*64 + w*8 + (lane>>3), physical colbyte (lane&7)*16,
  //    logical colbyte = phys ^ ((r&7)<<4) with r&7 == lane>>3.
  const int lrow = lane >> 3;
  const int lcbe = ((lane & 7) ^ lrow) << 3;  // bf16 element offset in k-tile
  const bf16* aS[2][LA];
#pragma unroll
  for (int h = 0; h < 2; h++)
#pragma unroll
    for (int j = 0; j < LA; j++)
      aS[h][j] =
          A + (size_t)(m0 + h * (BM / 2) + j * 64 + w * 8 + lrow) * K + lcbe;
  const bf16* bS[2][2];
#pragma unroll
  for (int h = 0; h < 2; h++)
#pragma unroll
    for (int j = 0; j < 2; j++)
      bS[h][j] =
          Bt + (size_t)(n0 + h * 128 + j * 64 + w * 8 + lrow) * K + lcbe;
  const int sdst = w * 1024;

  // ---- prologue staging, chronological order = vmcnt accounting:
  //      B(0) h0,h1 ; A(0) h0,h1 ; B(1) h0,h1 ; then vmcnt(4): tile 0 landed.
#pragma unroll
  for (int h = 0; h < 2; h++)
#pragma unroll
    for (int j = 0; j < 2; j++)
      GLDS16(bS[h][j], smem + ABYTES + h * 16384 + j * 8192 + sdst);
#pragma unroll
  for (int h = 0; h < 2; h++)
#pragma unroll
    for (int j = 0; j < LA; j++)
      GLDS16(aS[h][j], smem + h * (BM * 64) + j * 8192 + sdst);
#pragma unroll
  for (int h = 0; h < 2; h++)
#pragma unroll
    for (int j = 0; j < 2; j++)
      GLDS16(bS[h][j] + 64, smem + BUFB + ABYTES + h * 16384 + j * 8192 + sdst);
  asm volatile("s_waitcnt vmcnt(4)" ::: "memory");
  __builtin_amdgcn_s_barrier();

  const int swz = (lr & 7) << 4;
  const int abase = (wm * (BM / 2) + lr) * 128;
  const int bbase = ABYTES + (wn * 64 + lr) * 128;
  const int pcb0 = (quad * 16) ^ swz;  // kk=1 -> pcb0 ^ 64

  f32x4 acc[MREP][4] = {};
  bf16x8 af[MQ][2], bfr[2][2][2];

  for (int t = 0; t < NT; ++t) {
    char* cb_ = smem + (t & 1) * BUFB;
    char* nb_ = smem + ((t & 1) ^ 1) * BUFB;

    // ---------------- phase 0 : quadrant (0,0)
#pragma unroll
    for (int i4 = 0; i4 < MQ; i4++)
#pragma unroll
      for (int kk = 0; kk < 2; kk++)
        af[i4][kk] = *(const bf16x8*)(cb_ + abase + i4 * (16 * 128) +
                                      (pcb0 ^ (kk * 64)));
#pragma unroll
    for (int j2 = 0; j2 < 2; j2++)
#pragma unroll
      for (int kk = 0; kk < 2; kk++)
        bfr[0][j2][kk] = *(const bf16x8*)(cb_ + bbase + j2 * (16 * 128) +
                                          (pcb0 ^ (kk * 64)));
    if (t + 1 < NT) {
#pragma unroll
      for (int j = 0; j < LA; j++)
        GLDS16(aS[0][j] + (size_t)(t + 1) * 64, nb_ + j * 8192 + sdst);
    }
    __builtin_amdgcn_s_barrier();
    asm volatile("s_waitcnt lgkmcnt(0)" ::: "memory");
    __builtin_amdgcn_sched_barrier(0);
    __builtin_amdgcn_s_setprio(1);
#pragma unroll
    for (int i4 = 0; i4 < MQ; i4++)
#pragma unroll
      for (int j2 = 0; j2 < 2; j2++)
#pragma unroll
        for (int kk = 0; kk < 2; kk++)
          acc[i4][j2] = __builtin_amdgcn_mfma_f32_16x16x32_bf16(
              af[i4][kk], bfr[0][j2][kk], acc[i4][j2], 0, 0, 0);
    __builtin_amdgcn_s_setprio(0);
    __builtin_amdgcn_s_barrier();

    // ---------------- phase 1 : quadrant (0,1)
#pragma unroll
    for (int j2 = 0; j2 < 2; j2++)
#pragma unroll
      for (int kk = 0; kk < 2; kk++)
        bfr[1][j2][kk] =
            *(const bf16x8*)(cb_ + bbase + (32 + j2 * 16) * 128 +
                             (pcb0 ^ (kk * 64)));
    if (t + 1 < NT) {
#pragma unroll
      for (int j = 0; j < LA; j++)
        GLDS16(aS[1][j] + (size_t)(t + 1) * 64,
               nb_ + BM * 64 + j * 8192 + sdst);
    }
    __builtin_amdgcn_s_barrier();
    asm volatile("s_waitcnt lgkmcnt(0)" ::: "memory");
    __builtin_amdgcn_sched_barrier(0);
    __builtin_amdgcn_s_setprio(1);
#pragma unroll
    for (int i4 = 0; i4 < MQ; i4++)
#pragma unroll
      for (int j2 = 0; j2 < 2; j2++)
#pragma unroll
        for (int kk = 0; kk < 2; kk++)
          acc[i4][2 + j2] = __builtin_amdgcn_mfma_f32_16x16x32_bf16(
              af[i4][kk], bfr[1][j2][kk], acc[i4][2 + j2], 0, 0, 0);
    __builtin_amdgcn_s_setprio(0);
    __builtin_amdgcn_s_barrier();

    // ---------------- phase 2 : quadrant (1,0)
#pragma unroll
    for (int i4 = 0; i4 < MQ; i4++)
#pragma unroll
      for (int kk = 0; kk < 2; kk++)
        af[i4][kk] =
            *(const bf16x8*)(cb_ + abase + ((BM / 4) + i4 * 16) * 128 +
                             (pcb0 ^ (kk * 64)));
    if (t + 2 < NT) {
#pragma unroll
      for (int j = 0; j < 2; j++)
        GLDS16(bS[0][j] + (size_t)(t + 2) * 64,
               cb_ + ABYTES + j * 8192 + sdst);
    }
    __builtin_amdgcn_s_barrier();
    asm volatile("s_waitcnt lgkmcnt(0)" ::: "memory");
    __builtin_amdgcn_sched_barrier(0);
    __builtin_amdgcn_s_setprio(1);
#pragma unroll
    for (int i4 = 0; i4 < MQ; i4++)
#pragma unroll
      for (int j2 = 0; j2 < 2; j2++)
#pragma unroll
        for (int kk = 0; kk < 2; kk++)
          acc[MQ + i4][j2] = __builtin_amdgcn_mfma_f32_16x16x32_bf16(
              af[i4][kk], bfr[0][j2][kk], acc[MQ + i4][j2], 0, 0, 0);
    __builtin_amdgcn_s_setprio(0);
    __builtin_amdgcn_s_barrier();

    // ---------------- phase 3 : quadrant (1,1)
    if (t + 2 < NT) {
#pragma unroll
      for (int j = 0; j < 2; j++)
        GLDS16(bS[1][j] + (size_t)(t + 2) * 64,
               cb_ + ABYTES + 16384 + j * 8192 + sdst);
    }
    __builtin_amdgcn_s_barrier();
    asm volatile("s_waitcnt lgkmcnt(0)" ::: "memory");
    __builtin_amdgcn_sched_barrier(0);
    __builtin_amdgcn_s_setprio(1);
#pragma unroll
    for (int i4 = 0; i4 < MQ; i4++)
#pragma unroll
      for (int j2 = 0; j2 < 2; j2++)
#pragma unroll
        for (int kk = 0; kk < 2; kk++)
          acc[MQ + i4][2 + j2] = __builtin_amdgcn_mfma_f32_16x16x32_bf16(
              af[i4][kk], bfr[1][j2][kk], acc[MQ + i4][2 + j2], 0, 0, 0);
    __builtin_amdgcn_s_setprio(0);
    if (t + 2 < NT)
      asm volatile("s_waitcnt vmcnt(4)" ::: "memory");
    else
      asm volatile("s_waitcnt vmcnt(0)" ::: "memory");
    __builtin_amdgcn_s_barrier();
  }

  // ---------------- epilogue
#pragma unroll
  for (int ai = 0; ai < MREP; ai++)
#pragma unroll
    for (int bj = 0; bj < 4; bj++)
#pragma unroll
      for (int r = 0; r < 4; r++) {
        const size_t row = m0 + wm * (BM / 2) + ai * 16 + quad * 4 + r;
        const size_t col = n0 + wn * 64 + bj * 16 + lr;
        const float v = acc[ai][bj][r];
        if (MODE == 0)
          ((bf16*)Cout)[row * N + col] = (bf16)v;
        else
          ((float*)Cout)[row * N + col] = v + resid[row * N + col];
      }
}

// ---------------------------------------------------------------------------
// RoPE: qkv bf16 [2048][6144] -> qb bf16 [2048][4096] (scaled by 1/sqrt(D)),
//       kb bf16 [2048][1024]
// ---------------------------------------------------------------------------
__global__ __launch_bounds__(256) void rope_kernel(
    const bf16* __restrict__ qkv, const float* __restrict__ cosT,
    const float* __restrict__ sinT, bf16* __restrict__ qb,
    bf16* __restrict__ kb) {
  const int row = blockIdx.x;
  const int s = row & (S_LEN - 1);
  const bf16* base = qkv + (size_t)row * 6144;
  const float scale = 0.08838834764831845f;  // 1/sqrt(128)
  for (int p = threadIdx.x; p < 2560; p += 256) {
    const int hd = p >> 6;
    const int d = p & 63;
    const float c = cosT[s * HD + d], sn = sinT[s * HD + d];
    if (hd < NQ_H) {
      const bf16* qp = base + hd * HD;
      const float x1 = (float)qp[d], x2 = (float)qp[d + 64];
      bf16* o = qb + (size_t)row * H_DIM + hd * HD;
      o[d] = (bf16)((x1 * c - x2 * sn) * scale);
      o[d + 64] = (bf16)((x2 * c + x1 * sn) * scale);
    } else {
      const int kh = hd - NQ_H;
      const bf16* kp = base + H_DIM + kh * HD;
      const float x1 = (float)kp[d], x2 = (float)kp[d + 64];
      bf16* o = kb + (size_t)row * (NKV_H * HD) + kh * HD;
      o[d] = (bf16)(x1 * c - x2 * sn);
      o[d + 64] = (bf16)(x2 * c + x1 * sn);
    }
  }
}

// ---------------------------------------------------------------------------
// V transpose: qkv bf16 (v part at col 5120) -> vt bf16 [B][KV][128][S]
// ---------------------------------------------------------------------------
__global__ __launch_bounds__(256) void vtrans_kernel(
    const bf16* __restrict__ qkv, bf16* __restrict__ vt) {
  const int tx = threadIdx.x & 31, ty = threadIdx.x >> 5;
  const int s0 = blockIdx.x * 32, d0 = blockIdx.y * 32;
  const int b = blockIdx.z >> 3, kv = blockIdx.z & 7;
  __shared__ float t[32][33];
#pragma unroll
  for (int j = 0; j < 4; j++) {
    const int s = s0 + ty + j * 8;
    t[ty + j * 8][tx] =
        (float)qkv[(size_t)(b * S_LEN + s) * 6144 + 5120 + kv * HD + d0 + tx];
  }
  __syncthreads();
#pragma unroll
  for (int j = 0; j < 4; j++) {
    const int d = d0 + ty + j * 8;
    vt[((size_t)(b * NKV_H + kv) * HD + d) * S_LEN + s0 + tx] =
        (bf16)t[tx][ty + j * 8];
  }
}

// ---------------------------------------------------------------------------
// Flash attention. Grid (S/128, NQ, B), 256 threads (4 waves, 32 q-rows each).
// ---------------------------------------------------------------------------
__global__ __launch_bounds__(256) void attn_fwd(
    const bf16* __restrict__ Qb, const bf16* __restrict__ Kb,
    const bf16* __restrict__ Vtb, bf16* __restrict__ Ob) {
  __shared__ __align__(16) bf16 Ks[16 * 512];  // [4 ks][64 key][32 d]
  __shared__ __align__(16) bf16 Vs[16 * 512];  // [2 ks][128 d][32 key]
  __shared__ __align__(16) bf16 Ps[16 * 512];  // [2 ks][128 q][32 key]
  const int tid = threadIdx.x;
  const int wave = tid >> 6, lane = tid & 63;
  const int lr = lane & 15, quad = lane >> 4;
  const int qt = blockIdx.x, h = blockIdx.y, b = blockIdx.z;
  const int kv = h >> 2;
  const int qrow0 = qt * 128 + wave * 32;

  bf16x8 qf[2][4];
#pragma unroll
  for (int mi = 0; mi < 2; mi++)
#pragma unroll
    for (int ks = 0; ks < 4; ks++)
      qf[mi][ks] = *(const bf16x8*)&Qb[(size_t)(b * S_LEN + qrow0 + mi * 16 + lr) *
                                           H_DIM +
                                       h * HD + ks * 32 + quad * 8];

  f32x4 oacc[2][8] = {};
  float m_i[2][4], l_i[2][4];
#pragma unroll
  for (int mi = 0; mi < 2; mi++)
#pragma unroll
    for (int r = 0; r < 4; r++) {
      m_i[mi][r] = -__builtin_inff();
      l_i[mi][r] = 0.f;
    }

  const int nk = 2 * (qt + 1);
  const int maxrow = qrow0 + 31;
  const int srow = lane >> 2;
  const int scol = (lane & 3) * 8;

  for (int kt = 0; kt < nk; kt++) {
    const int k0 = kt * 64;
    __syncthreads();
#pragma unroll
    for (int i = 0; i < 4; i++) {
      const int c = wave * 4 + i;
      {
        const int ks = c >> 2, sc = c & 3;
        const int key = sc * 16 + srow;
        GLDS16(Kb + (size_t)(b * S_LEN + k0 + key) * (NKV_H * HD) + kv * HD +
                   ks * 32 + scol,
               Ks + c * 512);
      }
      {
        const int ks2 = c >> 3, sc2 = c & 7;
        const int d = sc2 * 16 + srow;
        GLDS16(Vtb + ((size_t)(b * NKV_H + kv) * HD + d) * S_LEN + k0 +
                   ks2 * 32 + scol,
               Vs + c * 512);
      }
    }
    __syncthreads();
    const bool active = (k0 <= maxrow);
    float alpha[2][4];
    if (active) {
      f32x4 sacc[2][4];
#pragma unroll
      for (int mi = 0; mi < 2; mi++)
#pragma unroll
        for (int nj = 0; nj < 4; nj++) sacc[mi][nj] = (f32x4){0.f, 0.f, 0.f, 0.f};
#pragma unroll
      for (int ks = 0; ks < 4; ks++) {
        bf16x8 kf[4];
#pragma unroll
        for (int nj = 0; nj < 4; nj++)
          kf[nj] = *(const bf16x8*)&Ks[ks * 2048 + (nj * 16 + lr) * 32 + quad * 8];
#pragma unroll
        for (int mi = 0; mi < 2; mi++)
#pragma unroll
          for (int nj = 0; nj < 4; nj++)
            sacc[mi][nj] = __builtin_amdgcn_mfma_f32_16x16x32_bf16(
                qf[mi][ks], kf[nj], sacc[mi][nj], 0, 0, 0);
      }
#pragma unroll
      for (int mi = 0; mi < 2; mi++) {
#pragma unroll
        for (int r = 0; r < 4; r++) {
          const int row = qrow0 + mi * 16 + quad * 4 + r;
          float best = -__builtin_inff();
#pragma unroll
          for (int nj = 0; nj < 4; nj++) {
            const int col = k0 + nj * 16 + lr;
            if (col > row) sacc[mi][nj][r] = -__builtin_inff();
            best = fmaxf(best, sacc[mi][nj][r]);
          }
#pragma unroll
          for (int m = 1; m < 16; m <<= 1)
            best = fmaxf(best, __shfl_xor(best, m));
          const float mnew = fmaxf(m_i[mi][r], best);
          alpha[mi][r] = __expf(m_i[mi][r] - mnew);
          m_i[mi][r] = mnew;
          float ssum = 0.f;
#pragma unroll
          for (int nj = 0; nj < 4; nj++) {
            const float p = __expf(sacc[mi][nj][r] - mnew);
            sacc[mi][nj][r] = p;
            ssum += p;
          }
#pragma unroll
          for (int m = 1; m < 16; m <<= 1) ssum += __shfl_xor(ssum, m);
          l_i[mi][r] = l_i[mi][r] * alpha[mi][r] + ssum;
        }
      }
#pragma unroll
      for (int mi = 0; mi < 2; mi++)
#pragma unroll
        for (int dj = 0; dj < 8; dj++)
#pragma unroll
          for (int r = 0; r < 4; r++) oacc[mi][dj][r] *= alpha[mi][r];
#pragma unroll
      for (int mi = 0; mi < 2; mi++)
#pragma unroll
        for (int nj = 0; nj < 4; nj++) {
          const int ks2 = nj >> 1;
          const int k32 = (nj & 1) * 16 + lr;
#pragma unroll
          for (int r = 0; r < 4; r++) {
            const int rowl = wave * 32 + mi * 16 + quad * 4 + r;
            Ps[ks2 * 4096 + rowl * 32 + k32] = (bf16)sacc[mi][nj][r];
          }
        }
    }
    __syncthreads();
    if (active) {
#pragma unroll
      for (int ks2 = 0; ks2 < 2; ks2++) {
        bf16x8 pf[2], vf[8];
#pragma unroll
        for (int mi = 0; mi < 2; mi++)
          pf[mi] = *(const bf16x8*)&Ps[ks2 * 4096 +
                                       (wave * 32 + mi * 16 + lr) * 32 + quad * 8];
#pragma unroll
        for (int dj = 0; dj < 8; dj++)
          vf[dj] = *(const bf16x8*)&Vs[ks2 * 4096 + (dj * 16 + lr) * 32 + quad * 8];
#pragma unroll
        for (int mi = 0; mi < 2; mi++)
#pragma unroll
          for (int dj = 0; dj < 8; dj++)
            oacc[mi][dj] = __builtin_amdgcn_mfma_f32_16x16x32_bf16(
                pf[mi], vf[dj], oacc[mi][dj], 0, 0, 0);
      }
    }
  }
#pragma unroll
  for (int mi = 0; mi < 2; mi++)
#pragma unroll
    for (int r = 0; r < 4; r++) {
      const float rinv = 1.f / l_i[mi][r];
      const size_t row = (size_t)b * S_LEN + qrow0 + mi * 16 + quad * 4 + r;
#pragma unroll
      for (int dj = 0; dj < 8; dj++)
        Ob[row * H_DIM + h * HD + dj * 16 + lr] =
            (bf16)(oacc[mi][dj][r] * rinv);
    }
}

// ---------------------------------------------------------------------------
// SwiGLU over interleaved GU [2048][22016] (gate tile / up tile alternating
// every 128 cols) -> act [2048][11008] bf16
// ---------------------------------------------------------------------------
__global__ __launch_bounds__(256) void swiglu_kernel(
    const bf16* __restrict__ gu, bf16* __restrict__ act) {
  const int gid = blockIdx.x * 256 + threadIdx.x;
  const int row = gid / 1376;        // 11008/8 groups per row
  const int c8 = (gid % 1376) * 8;
  const size_t gbase = (size_t)row * 22016 + (size_t)(c8 >> 7) * 256 + (c8 & 127);
  bf16x8 g = *(const bf16x8*)&gu[gbase];
  bf16x8 u = *(const bf16x8*)&gu[gbase + 128];
  bf16x8 o;
#pragma unroll
  for (int j = 0; j < 8; j++) {
    const float gf = (float)g[j];
    const float sg = gf / (1.f + __expf(-gf));
    o[j] = (bf16)(sg * (float)u[j]);
  }
  *(bf16x8*)&act[(size_t)row * I_DIM + c8] = o;
}

// ---------------------------------------------------------------------------
extern "C" void kernel_launch(void* const* d_in, const int* in_sizes, int n_in,
                              void* d_out, int out_size, void* d_ws,
                              size_t ws_size, hipStream_t stream) {
  const float* x = (const float*)d_in[0];
  const float* cosT = (const float*)d_in[1];
  const float* sinT = (const float*)d_in[2];
  const float* anw = (const float*)d_in[3];
  const float* fnw = (const float*)d_in[4];
  const float* wq = (const float*)d_in[5];
  const float* wk = (const float*)d_in[6];
  const float* wv = (const float*)d_in[7];
  const float* wo = (const float*)d_in[8];
  const float* wg = (const float*)d_in[9];
  const float* wu = (const float*)d_in[10];
  const float* wd = (const float*)d_in[11];

  char* ws = (char*)d_ws;
  size_t off = 0;
  auto alloc = [&](size_t bytes) -> void* {
    void* p = ws + off;
    off += (bytes + 255) & ~(size_t)255;
    return p;
  };
  const size_t M = 2048;
  bf16* WGUt = (bf16*)alloc(22016ULL * 4096 * 2);  // interleaved gate/up [N][K]
  bf16* WDt = (bf16*)alloc(4096ULL * I_DIM * 2);   // [4096][11008]
  char* R1 = (char*)alloc(90177536);               // WQKVt+WOt, later GU
  char* bufY = (char*)alloc(83886080);             // HIN..ATTN, later ACT
  float* H2 = (float*)alloc(M * 4096 * 4);
  bf16* MINb = (bf16*)alloc(M * 4096 * 2);

  bf16* WQKVt = (bf16*)R1;                       // [6144][4096]
  bf16* WOt = (bf16*)(R1 + 50331648);            // [4096][4096]
  bf16* GU = (bf16*)R1;                          // [2048][22016]
  bf16* HIN = (bf16*)bufY;                       // [2048][4096]
  bf16* QKVb = HIN + M * 4096;                   // [2048][6144]
  bf16* QB = QKVb + M * 6144;                    // [2048][4096]
  bf16* KB = QB + M * 4096;                      // [2048][1024]
  bf16* VT = KB + M * 1024;                      // [2][8][128][1024]
  bf16* ATTN = VT + M * 1024;                    // [2048][4096]
  bf16* ACT = (bf16*)bufY;                       // [2048][11008]

  // 1) weight transposes (fp32 -> bf16 [N][K]); gate/up interleaved
  wtrans64_kernel<<<dim3(64, 64), 256, 0, stream>>>(wq, WQKVt, 4096, 4096, 128, 0);
  wtrans64_kernel<<<dim3(16, 64), 256, 0, stream>>>(wk, WQKVt + 4096ULL * 4096, 4096, 1024, 128, 0);
  wtrans64_kernel<<<dim3(16, 64), 256, 0, stream>>>(wv, WQKVt + 5120ULL * 4096, 4096, 1024, 128, 0);
  wtrans64_kernel<<<dim3(64, 64), 256, 0, stream>>>(wo, WOt, 4096, 4096, 128, 0);
  wtrans64_kernel<<<dim3(172, 64), 256, 0, stream>>>(wg, WGUt, 4096, I_DIM, 256, 0);
  wtrans64_kernel<<<dim3(172, 64), 256, 0, stream>>>(wu, WGUt, 4096, I_DIM, 256, 128);
  wtrans64_kernel<<<dim3(64, 172), 256, 0, stream>>>(wd, WDt, I_DIM, 4096, 128, 0);

  // 2) attn rmsnorm -> bf16
  rmsnorm_kernel<<<2048, 256, 0, stream>>>(x, anw, HIN);
  // 3) fused QKV GEMM -> bf16 (8 m-tiles x 24 n-tiles)
  gemm256<256, 0><<<8 * 24, 512, 0, stream>>>(HIN, WQKVt, QKVb, nullptr, 6144, 4096, 3);
  // 4) rope (q scaled by 1/sqrt(D))
  rope_kernel<<<2048, 256, 0, stream>>>(QKVb, cosT, sinT, QB, KB);
  // 5) v transpose -> [b][kv][d][s] bf16
  vtrans_kernel<<<dim3(32, 4, 16), 256, 0, stream>>>(QKVb, VT);
  // 6) flash attention
  attn_fwd<<<dim3(8, 32, 2), 256, 0, stream>>>(QB, KB, VT, ATTN);
  // 7) WO GEMM + residual(x) -> H2 f32 (16 x 16 tiles, full machine)
  gemm256<128, 2><<<16 * 16, 512, 0, stream>>>(ATTN, WOt, H2, x, 4096, 4096, 4);
  // 8) ffn rmsnorm
  rmsnorm_kernel<<<2048, 256, 0, stream>>>(H2, fnw, MINb);
  // 9) fused gate+up GEMM (interleaved N=22016) -> bf16 (8 x 86 tiles)
  gemm256<256, 0><<<8 * 86, 512, 0, stream>>>(MINb, WGUt, GU, nullptr, 22016, 4096, 3);
  // 10) swiglu -> ACT
  swiglu_kernel<<<11008, 256, 0, stream>>>(GU, ACT);
  // 11) down GEMM + residual(H2) -> d_out f32 (16 x 16 tiles, K=11008)
  gemm256<128, 2><<<16 * 16, 512, 0, stream>>>(ACT, WDt, d_out, H2, 4096, 11008, 4);
}

// Round 2
// 1509.062 us; speedup vs baseline: 1.2500x; 1.0244x over previous
//
#include <hip/hip_runtime.h>
#include <cstdint>
#include <cstddef>

// ---------------------------------------------------------------------------
// Llama decoder layer, MI355X. B=2 S=1024 H=4096 NQ=32 NKV=8 D=128 I=11008.
// R4: GEMM phases re-cut as (m-half x k-half) so every phase's ds_reads feed
// the NEXT phase's MFMA (loads overlap MFMA; counted lgkmcnt, never 0
// mid-tile). 4 barriers/K-tile (was 8). Bijective XCD-chunked block swizzle.
// ---------------------------------------------------------------------------

typedef __bf16 bf16;
typedef __attribute__((ext_vector_type(8))) __bf16 bf16x8;
typedef __attribute__((ext_vector_type(4))) float f32x4;

#define GLDS16(gptr, lptr)                                                    \
  __builtin_amdgcn_global_load_lds(                                           \
      (const __attribute__((address_space(1))) void*)(gptr),                  \
      (__attribute__((address_space(3))) void*)(lptr), 16, 0, 0)

#define S_LEN 1024
#define H_DIM 4096
#define NQ_H 32
#define NKV_H 8
#define HD 128
#define I_DIM 11008

template <int N>
__device__ __forceinline__ void waitl() {
  asm volatile("s_waitcnt lgkmcnt(%0)" ::"n"(N) : "memory");
}
template <int N>
__device__ __forceinline__ void waitv() {
  asm volatile("s_waitcnt vmcnt(%0)" ::"n"(N) : "memory");
}
__device__ __forceinline__ void barr() {
  asm volatile("s_barrier" ::: "memory");
}

// ---------------------------------------------------------------------------
// Weight transpose + fp32->bf16, 64x64 tiles, vectorized.
// src [K][N] f32 -> dst[( (n>>7)*tile_stride + (n&127) + base )][K] bf16.
// ---------------------------------------------------------------------------
__global__ __launch_bounds__(256) void wtrans64_kernel(
    const float* __restrict__ src, bf16* __restrict__ dst, int K, int N,
    int tile_stride, int base) {
  const int tid = threadIdx.x;
  const int n0 = blockIdx.x * 64, k0 = blockIdx.y * 64;
  __shared__ float t[64][65];
  const int r = tid >> 4, c4 = (tid & 15) * 4;
#pragma unroll
  for (int j = 0; j < 4; j++) {
    const float4 v =
        *(const float4*)&src[(size_t)(k0 + r + j * 16) * N + n0 + c4];
    t[r + j * 16][c4 + 0] = v.x;
    t[r + j * 16][c4 + 1] = v.y;
    t[r + j * 16][c4 + 2] = v.z;
    t[r + j * 16][c4 + 3] = v.w;
  }
  __syncthreads();
  const int n = tid >> 2, kq = (tid & 3) * 16;
  bf16x8 o0, o1;
#pragma unroll
  for (int i = 0; i < 8; i++) {
    o0[i] = (bf16)t[kq + i][n];
    o1[i] = (bf16)t[kq + 8 + i][n];
  }
  const int ng = n0 + n;
  const size_t orow = (size_t)(ng >> 7) * tile_stride + (ng & 127) + base;
  *(bf16x8*)&dst[orow * K + k0 + kq] = o0;
  *(bf16x8*)&dst[orow * K + k0 + kq + 8] = o1;
}

// ---------------------------------------------------------------------------
// RMSNorm: x f32 [rows][4096] -> out bf16, one block per row
// ---------------------------------------------------------------------------
__global__ __launch_bounds__(256) void rmsnorm_kernel(
    const float* __restrict__ x, const float* __restrict__ w,
    bf16* __restrict__ out) {
  const int row = blockIdx.x;
  const float4* xr = (const float4*)(x + (size_t)row * H_DIM);
  float4 v[4];
  float s = 0.f;
#pragma unroll
  for (int i = 0; i < 4; i++) {
    v[i] = xr[threadIdx.x + i * 256];
    s += v[i].x * v[i].x + v[i].y * v[i].y + v[i].z * v[i].z + v[i].w * v[i].w;
  }
#pragma unroll
  for (int m = 1; m < 64; m <<= 1) s += __shfl_xor(s, m);
  __shared__ float red[4];
  if ((threadIdx.x & 63) == 0) red[threadIdx.x >> 6] = s;
  __syncthreads();
  s = red[0] + red[1] + red[2] + red[3];
  const float r = rsqrtf(s * (1.f / H_DIM) + 1e-5f);
  bf16* o = out + (size_t)row * H_DIM;
  const float4* wr = (const float4*)w;
#pragma unroll
  for (int i = 0; i < 4; i++) {
    float4 wv = wr[threadIdx.x + i * 256];
    int idx = (threadIdx.x + i * 256) * 4;
    o[idx + 0] = (bf16)(v[i].x * r * wv.x);
    o[idx + 1] = (bf16)(v[i].y * r * wv.y);
    o[idx + 2] = (bf16)(v[i].z * r * wv.z);
    o[idx + 3] = (bf16)(v[i].w * r * wv.w);
  }
}

// ---------------------------------------------------------------------------
// Pipelined GEMM TN: C[M][Ncols] = A[M][K](bf16) * Bt[Ncols][K](bf16)^T.
// BN=256. BM template (256/128). BK=64. 512 threads = 8 waves (2M x 4N),
// per-wave output (BM/2) x 64, MFMA 16x16x32.
//
// LDS: 2-K-tile ring, XOR-swizzled rows (128 B), staged by global_load_lds
// with pre-swizzled SOURCE address (linear dest), read with the same XOR.
//
// K-tile = 4 phases cut by (m-half mh, k-half kk):
//   p0: mfma(afA=mh0/kk0, bK0=kk0)  | load afB=(t,mh0,kk1), bK1=(t,kk1)
//   p1: mfma(afB, bK1) -> same acc  | load afA=(t,mh1,kk0)
//   p2: mfma(afA, bK0) -> acc[MQ..] | load afB=(t,mh1,kk1)
//   p3: mfma(afB, bK1) -> acc[MQ..] | load afA,bK0 = tile t+1 (after sync)
// Every phase's loads are consumed ONE phase later behind counted lgkmcnt
// (MQ or MQ+4) -> LDS service overlaps MFMA. One barrier per phase.
// Staging: A(t+1) halves at p0/p1 -> other buffer; B(t+2) halves at p2/p3
// -> current buffer's B region. Tile-boundary sync at p3-top:
// vmcnt(2) (only B(t+2)h0 stays in flight) + barrier, THEN the t+1
// pre-reads. vmcnt never drains to 0 until the tail.
// MODE 0: bf16 out. MODE 2: f32 out + resid add.
// ---------------------------------------------------------------------------
template <int BM, int MODE>
__global__ __launch_bounds__(512, 2) void gemm256(
    const bf16* __restrict__ A, const bf16* __restrict__ Bt,
    void* __restrict__ Cout, const float* __restrict__ resid, int N, int K,
    int mshift) {
  constexpr int MREP = BM / 32;         // m-fragments per wave (8 / 4)
  constexpr int MQ = MREP / 2;          // fragments per m-half (4 / 2)
  constexpr int LA = BM / 128;          // GLDS16 per thread per A-half (2 / 1)
  constexpr int ABYTES = BM * 128;      // A region bytes per buffer
  constexpr int BUFB = ABYTES + 32768;  // + B region (256 rows x 128 B)
  __shared__ __align__(16) char smem[2 * BUFB];

  const int tid = threadIdx.x;
  const int w = tid >> 6, lane = tid & 63;
  const int lr = lane & 15, quad = lane >> 4;
  const int wm = w & 1, wn = w >> 1;
  // bijective XCD-chunked swizzle (grid divisible by 8): HW block b lands on
  // XCD b%8; give each XCD a contiguous run of tile-ids so the 8/16 m-blocks
  // sharing one B panel stay on one XCD's L2.
  const int bid = (blockIdx.x & 7) * ((int)gridDim.x >> 3) + (blockIdx.x >> 3);
  const int m0 = (bid & ((1 << mshift) - 1)) * BM;
  const int n0 = (bid >> mshift) * 256;
  const int NT = K >> 6;

  // staging source geometry: linear LDS dest o = j*8192 + w*1024 + lane*16
  // -> row r = j*64 + w*8 + (lane>>3), physical colbyte (lane&7)*16,
  //    logical colbyte = phys ^ ((r&7)<<4) with r&7 == lane>>3.
  const int lrow = lane >> 3;
  const int lcbe = ((lane & 7) ^ lrow) << 3;  // bf16 element offset in k-tile
  const bf16* aS[2][LA];
#pragma unroll
  for (int h = 0; h < 2; h++)
#pragma unroll
    for (int j = 0; j < LA; j++)
      aS[h][j] =
          A + (size_t)(m0 + h * (BM / 2) + j * 64 + w * 8 + lrow) * K + lcbe;
  const bf16* bS[2][2];
#pragma unroll
  for (int h = 0; h < 2; h++)
#pragma unroll
    for (int j = 0; j < 2; j++)
      bS[h][j] =
          Bt + (size_t)(n0 + h * 128 + j * 64 + w * 8 + lrow) * K + lcbe;
  const int sdst = w * 1024;

  // ---- prologue staging, chronological order = vmcnt accounting:
  //      B(0) h0,h1 ; A(0) h0,h1 ; B(1) h0,h1 ; then vmcnt(4): tile 0 landed.
#pragma unroll
  for (int h = 0; h < 2; h++)
#pragma unroll
    for (int j = 0; j < 2; j++)
      GLDS16(bS[h][j], smem + ABYTES + h * 16384 + j * 8192 + sdst);
#pragma unroll
  for (int h = 0; h < 2; h++)
#pragma unroll
    for (int j = 0; j < LA; j++)
      GLDS16(aS[h][j], smem + h * (BM * 64) + j * 8192 + sdst);
#pragma unroll
  for (int h = 0; h < 2; h++)
#pragma unroll
    for (int j = 0; j < 2; j++)
      GLDS16(bS[h][j] + 64, smem + BUFB + ABYTES + h * 16384 + j * 8192 + sdst);
  waitv<4>();
  barr();

  const int swz = (lr & 7) << 4;
  const int abase = (wm * (BM / 2) + lr) * 128;
  const int bbase = ABYTES + (wn * 64 + lr) * 128;
  const int pcb0 = (quad * 16) ^ swz;  // kk=1 -> pcb0 ^ 64

  f32x4 acc[MREP][4] = {};
  bf16x8 afA[MQ], afB[MQ], bK0[4], bK1[4];

  // prologue register pre-reads: tile 0, (mh0, kk0) -- consumed at p0 of t=0
#pragma unroll
  for (int i = 0; i < MQ; i++)
    afA[i] = *(const bf16x8*)(smem + abase + i * 2048 + pcb0);
#pragma unroll
  for (int j = 0; j < 4; j++)
    bK0[j] = *(const bf16x8*)(smem + bbase + j * 2048 + pcb0);

  for (int t = 0; t < NT; ++t) {
    char* cb_ = smem + (t & 1) * BUFB;
    char* nb_ = smem + ((t & 1) ^ 1) * BUFB;

    // ---------------- phase 0: mfma(mh0,kk0) | load (mh0,kk1)+(kk1)
    barr();
#pragma unroll
    for (int i = 0; i < MQ; i++)
      afB[i] = *(const bf16x8*)(cb_ + abase + i * 2048 + (pcb0 ^ 64));
#pragma unroll
    for (int j = 0; j < 4; j++)
      bK1[j] = *(const bf16x8*)(cb_ + bbase + j * 2048 + (pcb0 ^ 64));
    if (t + 1 < NT) {
#pragma unroll
      for (int j = 0; j < LA; j++)
        GLDS16(aS[0][j] + (size_t)(t + 1) * 64, nb_ + j * 8192 + sdst);
    }
    waitl<MQ + 4>();  // drain prev-phase loads; keep this phase's in flight
    __builtin_amdgcn_sched_barrier(0);
    __builtin_amdgcn_s_setprio(1);
#pragma unroll
    for (int i = 0; i < MQ; i++)
#pragma unroll
      for (int j = 0; j < 4; j++)
        acc[i][j] = __builtin_amdgcn_mfma_f32_16x16x32_bf16(afA[i], bK0[j],
                                                            acc[i][j], 0, 0, 0);
    __builtin_amdgcn_s_setprio(0);

    // ---------------- phase 1: mfma(mh0,kk1) | load (mh1,kk0)
    barr();
#pragma unroll
    for (int i = 0; i < MQ; i++)
      afA[i] = *(const bf16x8*)(cb_ + abase + (BM / 4 + i * 16) * 128 + pcb0);
    if (t + 1 < NT) {
#pragma unroll
      for (int j = 0; j < LA; j++)
        GLDS16(aS[1][j] + (size_t)(t + 1) * 64,
               nb_ + BM * 64 + j * 8192 + sdst);
    }
    waitl<MQ>();
    __builtin_amdgcn_sched_barrier(0);
    __builtin_amdgcn_s_setprio(1);
#pragma unroll
    for (int i = 0; i < MQ; i++)
#pragma unroll
      for (int j = 0; j < 4; j++)
        acc[i][j] = __builtin_amdgcn_mfma_f32_16x16x32_bf16(afB[i], bK1[j],
                                                            acc[i][j], 0, 0, 0);
    __builtin_amdgcn_s_setprio(0);

    // ---------------- phase 2: mfma(mh1,kk0) | load (mh1,kk1)
    barr();
#pragma unroll
    for (int i = 0; i < MQ; i++)
      afB[i] =
          *(const bf16x8*)(cb_ + abase + (BM / 4 + i * 16) * 128 + (pcb0 ^ 64));
    if (t + 2 < NT) {
#pragma unroll
      for (int j = 0; j < 2; j++)
        GLDS16(bS[0][j] + (size_t)(t + 2) * 64, cb_ + ABYTES + j * 8192 + sdst);
    }
    waitl<MQ>();
    __builtin_amdgcn_sched_barrier(0);
    __builtin_amdgcn_s_setprio(1);
#pragma unroll
    for (int i = 0; i < MQ; i++)
#pragma unroll
      for (int j = 0; j < 4; j++)
        acc[MQ + i][j] = __builtin_amdgcn_mfma_f32_16x16x32_bf16(
            afA[i], bK0[j], acc[MQ + i][j], 0, 0, 0);
    __builtin_amdgcn_s_setprio(0);

    // ---------------- phase 3: mfma(mh1,kk1) | load tile t+1 (mh0,kk0)+(kk0)
    if (t + 2 < NT)
      waitv<2>();  // A(t+1),B(t+1) landed; B(t+2)h0 stays in flight
    else
      waitv<0>();
    barr();
#pragma unroll
    for (int i = 0; i < MQ; i++)
      afA[i] = *(const bf16x8*)(nb_ + abase + i * 2048 + pcb0);
#pragma unroll
    for (int j = 0; j < 4; j++)
      bK0[j] = *(const bf16x8*)(nb_ + bbase + j * 2048 + pcb0);
    if (t + 2 < NT) {
#pragma unroll
      for (int j = 0; j < 2; j++)
        GLDS16(bS[1][j] + (size_t)(t + 2) * 64,
               cb_ + ABYTES + 16384 + j * 8192 + sdst);
    }
    waitl<MQ + 4>();  // drain p2's afB loads; keep t+1 pre-reads in flight
    __builtin_amdgcn_sched_barrier(0);
    __builtin_amdgcn_s_setprio(1);
#pragma unroll
    for (int i = 0; i < MQ; i++)
#pragma unroll
      for (int j = 0; j < 4; j++)
        acc[MQ + i][j] = __builtin_amdgcn_mfma_f32_16x16x32_bf16(
            afB[i], bK1[j], acc[MQ + i][j], 0, 0, 0);
    __builtin_amdgcn_s_setprio(0);
  }

  // ---------------- epilogue
#pragma unroll
  for (int ai = 0; ai < MREP; ai++)
#pragma unroll
    for (int bj = 0; bj < 4; bj++)
#pragma unroll
      for (int r = 0; r < 4; r++) {
        const size_t row = m0 + wm * (BM / 2) + ai * 16 + quad * 4 + r;
        const size_t col = n0 + wn * 64 + bj * 16 + lr;
        const float v = acc[ai][bj][r];
        if (MODE == 0)
          ((bf16*)Cout)[row * N + col] = (bf16)v;
        else
          ((float*)Cout)[row * N + col] = v + resid[row * N + col];
      }
}

// ---------------------------------------------------------------------------
// RoPE: qkv bf16 [2048][6144] -> qb bf16 [2048][4096] (scaled by 1/sqrt(D)),
//       kb bf16 [2048][1024]
// ---------------------------------------------------------------------------
__global__ __launch_bounds__(256) void rope_kernel(
    const bf16* __restrict__ qkv, const float* __restrict__ cosT,
    const float* __restrict__ sinT, bf16* __restrict__ qb,
    bf16* __restrict__ kb) {
  const int row = blockIdx.x;
  const int s = row & (S_LEN - 1);
  const bf16* base = qkv + (size_t)row * 6144;
  const float scale = 0.08838834764831845f;  // 1/sqrt(128)
  for (int p = threadIdx.x; p < 2560; p += 256) {
    const int hd = p >> 6;
    const int d = p & 63;
    const float c = cosT[s * HD + d], sn = sinT[s * HD + d];
    if (hd < NQ_H) {
      const bf16* qp = base + hd * HD;
      const float x1 = (float)qp[d], x2 = (float)qp[d + 64];
      bf16* o = qb + (size_t)row * H_DIM + hd * HD;
      o[d] = (bf16)((x1 * c - x2 * sn) * scale);
      o[d + 64] = (bf16)((x2 * c + x1 * sn) * scale);
    } else {
      const int kh = hd - NQ_H;
      const bf16* kp = base + H_DIM + kh * HD;
      const float x1 = (float)kp[d], x2 = (float)kp[d + 64];
      bf16* o = kb + (size_t)row * (NKV_H * HD) + kh * HD;
      o[d] = (bf16)(x1 * c - x2 * sn);
      o[d + 64] = (bf16)(x2 * c + x1 * sn);
    }
  }
}

// ---------------------------------------------------------------------------
// V transpose: qkv bf16 (v part at col 5120) -> vt bf16 [B][KV][128][S]
// ---------------------------------------------------------------------------
__global__ __launch_bounds__(256) void vtrans_kernel(
    const bf16* __restrict__ qkv, bf16* __restrict__ vt) {
  const int tx = threadIdx.x & 31, ty = threadIdx.x >> 5;
  const int s0 = blockIdx.x * 32, d0 = blockIdx.y * 32;
  const int b = blockIdx.z >> 3, kv = blockIdx.z & 7;
  __shared__ float t[32][33];
#pragma unroll
  for (int j = 0; j < 4; j++) {
    const int s = s0 + ty + j * 8;
    t[ty + j * 8][tx] =
        (float)qkv[(size_t)(b * S_LEN + s) * 6144 + 5120 + kv * HD + d0 + tx];
  }
  __syncthreads();
#pragma unroll
  for (int j = 0; j < 4; j++) {
    const int d = d0 + ty + j * 8;
    vt[((size_t)(b * NKV_H + kv) * HD + d) * S_LEN + s0 + tx] =
        (bf16)t[tx][ty + j * 8];
  }
}

// ---------------------------------------------------------------------------
// Flash attention. Grid (S/128, NQ, B), 256 threads (4 waves, 32 q-rows each).
// ---------------------------------------------------------------------------
__global__ __launch_bounds__(256) void attn_fwd(
    const bf16* __restrict__ Qb, const bf16* __restrict__ Kb,
    const bf16* __restrict__ Vtb, bf16* __restrict__ Ob) {
  __shared__ __align__(16) bf16 Ks[16 * 512];  // [4 ks][64 key][32 d]
  __shared__ __align__(16) bf16 Vs[16 * 512];  // [2 ks][128 d][32 key]
  __shared__ __align__(16) bf16 Ps[16 * 512];  // [2 ks][128 q][32 key]
  const int tid = threadIdx.x;
  const int wave = tid >> 6, lane = tid & 63;
  const int lr = lane & 15, quad = lane >> 4;
  const int qt = blockIdx.x, h = blockIdx.y, b = blockIdx.z;
  const int kv = h >> 2;
  const int qrow0 = qt * 128 + wave * 32;

  bf16x8 qf[2][4];
#pragma unroll
  for (int mi = 0; mi < 2; mi++)
#pragma unroll
    for (int ks = 0; ks < 4; ks++)
      qf[mi][ks] = *(const bf16x8*)&Qb[(size_t)(b * S_LEN + qrow0 + mi * 16 + lr) *
                                           H_DIM +
                                       h * HD + ks * 32 + quad * 8];

  f32x4 oacc[2][8] = {};
  float m_i[2][4], l_i[2][4];
#pragma unroll
  for (int mi = 0; mi < 2; mi++)
#pragma unroll
    for (int r = 0; r < 4; r++) {
      m_i[mi][r] = -__builtin_inff();
      l_i[mi][r] = 0.f;
    }

  const int nk = 2 * (qt + 1);
  const int maxrow = qrow0 + 31;
  const int srow = lane >> 2;
  const int scol = (lane & 3) * 8;

  for (int kt = 0; kt < nk; kt++) {
    const int k0 = kt * 64;
    __syncthreads();
#pragma unroll
    for (int i = 0; i < 4; i++) {
      const int c = wave * 4 + i;
      {
        const int ks = c >> 2, sc = c & 3;
        const int key = sc * 16 + srow;
        GLDS16(Kb + (size_t)(b * S_LEN + k0 + key) * (NKV_H * HD) + kv * HD +
                   ks * 32 + scol,
               Ks + c * 512);
      }
      {
        const int ks2 = c >> 3, sc2 = c & 7;
        const int d = sc2 * 16 + srow;
        GLDS16(Vtb + ((size_t)(b * NKV_H + kv) * HD + d) * S_LEN + k0 +
                   ks2 * 32 + scol,
               Vs + c * 512);
      }
    }
    __syncthreads();
    const bool active = (k0 <= maxrow);
    float alpha[2][4];
    if (active) {
      f32x4 sacc[2][4];
#pragma unroll
      for (int mi = 0; mi < 2; mi++)
#pragma unroll
        for (int nj = 0; nj < 4; nj++) sacc[mi][nj] = (f32x4){0.f, 0.f, 0.f, 0.f};
#pragma unroll
      for (int ks = 0; ks < 4; ks++) {
        bf16x8 kf[4];
#pragma unroll
        for (int nj = 0; nj < 4; nj++)
          kf[nj] = *(const bf16x8*)&Ks[ks * 2048 + (nj * 16 + lr) * 32 + quad * 8];
#pragma unroll
        for (int mi = 0; mi < 2; mi++)
#pragma unroll
          for (int nj = 0; nj < 4; nj++)
            sacc[mi][nj] = __builtin_amdgcn_mfma_f32_16x16x32_bf16(
                qf[mi][ks], kf[nj], sacc[mi][nj], 0, 0, 0);
      }
#pragma unroll
      for (int mi = 0; mi < 2; mi++) {
#pragma unroll
        for (int r = 0; r < 4; r++) {
          const int row = qrow0 + mi * 16 + quad * 4 + r;
          float best = -__builtin_inff();
#pragma unroll
          for (int nj = 0; nj < 4; nj++) {
            const int col = k0 + nj * 16 + lr;
            if (col > row) sacc[mi][nj][r] = -__builtin_inff();
            best = fmaxf(best, sacc[mi][nj][r]);
          }
#pragma unroll
          for (int m = 1; m < 16; m <<= 1)
            best = fmaxf(best, __shfl_xor(best, m));
          const float mnew = fmaxf(m_i[mi][r], best);
          alpha[mi][r] = __expf(m_i[mi][r] - mnew);
          m_i[mi][r] = mnew;
          float ssum = 0.f;
#pragma unroll
          for (int nj = 0; nj < 4; nj++) {
            const float p = __expf(sacc[mi][nj][r] - mnew);
            sacc[mi][nj][r] = p;
            ssum += p;
          }
#pragma unroll
          for (int m = 1; m < 16; m <<= 1) ssum += __shfl_xor(ssum, m);
          l_i[mi][r] = l_i[mi][r] * alpha[mi][r] + ssum;
        }
      }
#pragma unroll
      for (int mi = 0; mi < 2; mi++)
#pragma unroll
        for (int dj = 0; dj < 8; dj++)
#pragma unroll
          for (int r = 0; r < 4; r++) oacc[mi][dj][r] *= alpha[mi][r];
#pragma unroll
      for (int mi = 0; mi < 2; mi++)
#pragma unroll
        for (int nj = 0; nj < 4; nj++) {
          const int ks2 = nj >> 1;
          const int k32 = (nj & 1) * 16 + lr;
#pragma unroll
          for (int r = 0; r < 4; r++) {
            const int rowl = wave * 32 + mi * 16 + quad * 4 + r;
            Ps[ks2 * 4096 + rowl * 32 + k32] = (bf16)sacc[mi][nj][r];
          }
        }
    }
    __syncthreads();
    if (active) {
#pragma unroll
      for (int ks2 = 0; ks2 < 2; ks2++) {
        bf16x8 pf[2], vf[8];
#pragma unroll
        for (int mi = 0; mi < 2; mi++)
          pf[mi] = *(const bf16x8*)&Ps[ks2 * 4096 +
                                       (wave * 32 + mi * 16 + lr) * 32 + quad * 8];
#pragma unroll
        for (int dj = 0; dj < 8; dj++)
          vf[dj] = *(const bf16x8*)&Vs[ks2 * 4096 + (dj * 16 + lr) * 32 + quad * 8];
#pragma unroll
        for (int mi = 0; mi < 2; mi++)
#pragma unroll
          for (int dj = 0; dj < 8; dj++)
            oacc[mi][dj] = __builtin_amdgcn_mfma_f32_16x16x32_bf16(
                pf[mi], vf[dj], oacc[mi][dj], 0, 0, 0);
      }
    }
  }
#pragma unroll
  for (int mi = 0; mi < 2; mi++)
#pragma unroll
    for (int r = 0; r < 4; r++) {
      const float rinv = 1.f / l_i[mi][r];
      const size_t row = (size_t)b * S_LEN + qrow0 + mi * 16 + quad * 4 + r;
#pragma unroll
      for (int dj = 0; dj < 8; dj++)
        Ob[row * H_DIM + h * HD + dj * 16 + lr] =
            (bf16)(oacc[mi][dj][r] * rinv);
    }
}

// ---------------------------------------------------------------------------
// SwiGLU over interleaved GU [2048][22016] (gate tile / up tile alternating
// every 128 cols) -> act [2048][11008] bf16
// ---------------------------------------------------------------------------
__global__ __launch_bounds__(256) void swiglu_kernel(
    const bf16* __restrict__ gu, bf16* __restrict__ act) {
  const int gid = blockIdx.x * 256 + threadIdx.x;
  const int row = gid / 1376;        // 11008/8 groups per row
  const int c8 = (gid % 1376) * 8;
  const size_t gbase = (size_t)row * 22016 + (size_t)(c8 >> 7) * 256 + (c8 & 127);
  bf16x8 g = *(const bf16x8*)&gu[gbase];
  bf16x8 u = *(const bf16x8*)&gu[gbase + 128];
  bf16x8 o;
#pragma unroll
  for (int j = 0; j < 8; j++) {
    const float gf = (float)g[j];
    const float sg = gf / (1.f + __expf(-gf));
    o[j] = (bf16)(sg * (float)u[j]);
  }
  *(bf16x8*)&act[(size_t)row * I_DIM + c8] = o;
}

// ---------------------------------------------------------------------------
extern "C" void kernel_launch(void* const* d_in, const int* in_sizes, int n_in,
                              void* d_out, int out_size, void* d_ws,
                              size_t ws_size, hipStream_t stream) {
  const float* x = (const float*)d_in[0];
  const float* cosT = (const float*)d_in[1];
  const float* sinT = (const float*)d_in[2];
  const float* anw = (const float*)d_in[3];
  const float* fnw = (const float*)d_in[4];
  const float* wq = (const float*)d_in[5];
  const float* wk = (const float*)d_in[6];
  const float* wv = (const float*)d_in[7];
  const float* wo = (const float*)d_in[8];
  const float* wg = (const float*)d_in[9];
  const float* wu = (const float*)d_in[10];
  const float* wd = (const float*)d_in[11];

  char* ws = (char*)d_ws;
  size_t off = 0;
  auto alloc = [&](size_t bytes) -> void* {
    void* p = ws + off;
    off += (bytes + 255) & ~(size_t)255;
    return p;
  };
  const size_t M = 2048;
  bf16* WGUt = (bf16*)alloc(22016ULL * 4096 * 2);  // interleaved gate/up [N][K]
  bf16* WDt = (bf16*)alloc(4096ULL * I_DIM * 2);   // [4096][11008]
  char* R1 = (char*)alloc(90177536);               // WQKVt+WOt, later GU
  char* bufY = (char*)alloc(83886080);             // HIN..ATTN, later ACT
  float* H2 = (float*)alloc(M * 4096 * 4);
  bf16* MINb = (bf16*)alloc(M * 4096 * 2);

  bf16* WQKVt = (bf16*)R1;                       // [6144][4096]
  bf16* WOt = (bf16*)(R1 + 50331648);            // [4096][4096]
  bf16* GU = (bf16*)R1;                          // [2048][22016]
  bf16* HIN = (bf16*)bufY;                       // [2048][4096]
  bf16* QKVb = HIN + M * 4096;                   // [2048][6144]
  bf16* QB = QKVb + M * 6144;                    // [2048][4096]
  bf16* KB = QB + M * 4096;                      // [2048][1024]
  bf16* VT = KB + M * 1024;                      // [2][8][128][1024]
  bf16* ATTN = VT + M * 1024;                    // [2048][4096]
  bf16* ACT = (bf16*)bufY;                       // [2048][11008]

  // 1) weight transposes (fp32 -> bf16 [N][K]); gate/up interleaved
  wtrans64_kernel<<<dim3(64, 64), 256, 0, stream>>>(wq, WQKVt, 4096, 4096, 128, 0);
  wtrans64_kernel<<<dim3(16, 64), 256, 0, stream>>>(wk, WQKVt + 4096ULL * 4096, 4096, 1024, 128, 0);
  wtrans64_kernel<<<dim3(16, 64), 256, 0, stream>>>(wv, WQKVt + 5120ULL * 4096, 4096, 1024, 128, 0);
  wtrans64_kernel<<<dim3(64, 64), 256, 0, stream>>>(wo, WOt, 4096, 4096, 128, 0);
  wtrans64_kernel<<<dim3(172, 64), 256, 0, stream>>>(wg, WGUt, 4096, I_DIM, 256, 0);
  wtrans64_kernel<<<dim3(172, 64), 256, 0, stream>>>(wu, WGUt, 4096, I_DIM, 256, 128);
  wtrans64_kernel<<<dim3(64, 172), 256, 0, stream>>>(wd, WDt, I_DIM, 4096, 128, 0);

  // 2) attn rmsnorm -> bf16
  rmsnorm_kernel<<<2048, 256, 0, stream>>>(x, anw, HIN);
  // 3) fused QKV GEMM -> bf16 (8 m-tiles x 24 n-tiles)
  gemm256<256, 0><<<8 * 24, 512, 0, stream>>>(HIN, WQKVt, QKVb, nullptr, 6144, 4096, 3);
  // 4) rope (q scaled by 1/sqrt(D))
  rope_kernel<<<2048, 256, 0, stream>>>(QKVb, cosT, sinT, QB, KB);
  // 5) v transpose -> [b][kv][d][s] bf16
  vtrans_kernel<<<dim3(32, 4, 16), 256, 0, stream>>>(QKVb, VT);
  // 6) flash attention
  attn_fwd<<<dim3(8, 32, 2), 256, 0, stream>>>(QB, KB, VT, ATTN);
  // 7) WO GEMM + residual(x) -> H2 f32 (16 x 16 tiles, full machine)
  gemm256<128, 2><<<16 * 16, 512, 0, stream>>>(ATTN, WOt, H2, x, 4096, 4096, 4);
  // 8) ffn rmsnorm
  rmsnorm_kernel<<<2048, 256, 0, stream>>>(H2, fnw, MINb);
  // 9) fused gate+up GEMM (interleaved N=22016) -> bf16 (8 x 86 tiles)
  gemm256<256, 0><<<8 * 86, 512, 0, stream>>>(MINb, WGUt, GU, nullptr, 22016, 4096, 3);
  // 10) swiglu -> ACT
  swiglu_kernel<<<11008, 256, 0, stream>>>(GU, ACT);
  // 11) down GEMM + residual(H2) -> d_out f32 (16 x 16 tiles, K=11008)
  gemm256<128, 2><<<16 * 16, 512, 0, stream>>>(ACT, WDt, d_out, H2, 4096, 11008, 4);
}